// Round 7
// baseline (30481.570 us; speedup 1.0000x reference)
//
#include <hip/hip_runtime.h>
#include <hip/hip_bf16.h>

#define S_LEN 4096
#define IDIM  2048
#define HDIM  2048
#define G4    8192
#define NB    256
#define TPB   512
#define SENT  0x7FC00000u   // qNaN: h = sigmoid*tanh of finite data, never NaN

typedef __attribute__((ext_vector_type(2))) float  f32x2;
typedef __attribute__((ext_vector_type(4))) float  f32x4;
typedef __attribute__((ext_vector_type(8))) short  bf16x8;

// packed fp32 FMA: acc = w*h + acc (2 MACs/instruction)
#define PKFMA(acc, w, h) \
  asm("v_pk_fma_f32 %0, %1, %2, %0" : "+v"(acc) : "v"(w), "v"(h))

// ---- bf16 helpers ----
__device__ __forceinline__ unsigned short f2bf(float f) {
  unsigned u = __float_as_uint(f);
  unsigned r = (u + 0x7FFFu + ((u >> 16) & 1u)) >> 16;   // RNE
  return (unsigned short)r;
}
__device__ __forceinline__ float bf2f(unsigned short h) {
  return __uint_as_float(((unsigned)h) << 16);
}
__device__ __forceinline__ float sigmoid_fast(float x) {
  return __builtin_amdgcn_rcpf(1.f + __expf(-x));
}
__device__ __forceinline__ float tanh_fast(float x) {
  return 1.f - 2.f * __builtin_amdgcn_rcpf(__expf(2.f * x) + 1.f);
}

// =====================================================================
// Kernel 0: fill out with sentinel (per-element readiness ground state)
// =====================================================================
__global__ __launch_bounds__(256) void fill_sentinel(unsigned long long* p) {
  const unsigned long long v =
      ((unsigned long long)SENT << 32) | (unsigned long long)SENT;
  const int n = S_LEN * HDIM / 2;
  for (int i = blockIdx.x * 256 + threadIdx.x; i < n; i += gridDim.x * 256)
    p[i] = v;
}

// =====================================================================
// Kernel 1: xg = x·W_ihᵀ + b_ih + b_hh, bf16 MFMA. (proven, ~0.1 ms)
// =====================================================================
#define BM 128
#define BKK 32
#define LDK 40

__global__ __launch_bounds__(256) void gemm_xg_mfma(
    const float* __restrict__ x, const float* __restrict__ Wih,
    const float* __restrict__ bih, const float* __restrict__ bhh,
    unsigned short* __restrict__ xg) {
  __shared__ unsigned short As[BM][LDK];
  __shared__ unsigned short Bs[BM][LDK];

  const int t = threadIdx.x;
  const int lane = t & 63, wid = t >> 6;
  const int wr = wid >> 1, wc = wid & 1;

  int bid = ((int)blockIdx.x & 7) * 256 + ((int)blockIdx.x >> 3);
  const int s0 = (bid >> 6) * BM;
  const int j0 = (bid & 63) * BM;

  f32x4 acc[4][4] = {};

  float bias[4];
#pragma unroll
  for (int n = 0; n < 4; ++n) {
    const int col = j0 + wc * 64 + n * 16 + (lane & 15);
    bias[n] = bih[col] + bhh[col];
  }

  for (int k0 = 0; k0 < IDIM; k0 += BKK) {
    float4 va[4], vb[4];
#pragma unroll
    for (int u = 0; u < 4; ++u) {
      const int f = t + 256 * u;
      const int row = f >> 3, kc = (f & 7) * 4;
      va[u] = *(const float4*)&x  [(size_t)(s0 + row) * IDIM + k0 + kc];
      vb[u] = *(const float4*)&Wih[(size_t)(j0 + row) * IDIM + k0 + kc];
    }
    __syncthreads();
#pragma unroll
    for (int u = 0; u < 4; ++u) {
      const int f = t + 256 * u;
      const int row = f >> 3, kc = (f & 7) * 4;
      ushort4 pa, pb;
      pa.x = f2bf(va[u].x); pa.y = f2bf(va[u].y);
      pa.z = f2bf(va[u].z); pa.w = f2bf(va[u].w);
      pb.x = f2bf(vb[u].x); pb.y = f2bf(vb[u].y);
      pb.z = f2bf(vb[u].z); pb.w = f2bf(vb[u].w);
      *(ushort4*)&As[row][kc] = pa;
      *(ushort4*)&Bs[row][kc] = pb;
    }
    __syncthreads();

    const int fr = lane & 15, koff = (lane >> 4) * 8;
    bf16x8 a[4], bfr[4];
#pragma unroll
    for (int m = 0; m < 4; ++m)
      a[m] = *(const bf16x8*)&As[wr * 64 + m * 16 + fr][koff];
#pragma unroll
    for (int n = 0; n < 4; ++n)
      bfr[n] = *(const bf16x8*)&Bs[wc * 64 + n * 16 + fr][koff];
#pragma unroll
    for (int m = 0; m < 4; ++m)
#pragma unroll
      for (int n = 0; n < 4; ++n)
        acc[m][n] = __builtin_amdgcn_mfma_f32_16x16x32_bf16(
            a[m], bfr[n], acc[m][n], 0, 0, 0);
  }

#pragma unroll
  for (int m = 0; m < 4; ++m) {
    const int row0 = s0 + wr * 64 + m * 16 + (lane >> 4) * 4;
#pragma unroll
    for (int n = 0; n < 4; ++n) {
      const int col = j0 + wc * 64 + n * 16 + (lane & 15);
#pragma unroll
      for (int r = 0; r < 4; ++r)
        xg[(size_t)(row0 + r) * G4 + col] = f2bf(acc[m][n][r] + bias[n]);
    }
  }
}

// =====================================================================
// Kernel 2: persistent scan.
//  WEIGHTS: 64 named f32x2 scalars per thread (512B). Named scalars are
//  SROA-proof — rounds 1-6 used arrays, which fell to scratch (VGPR=84)
//  and re-streamed 64MB/step through L2-miss: THE hidden floor.
//  SYNC: single-RT sentinel. lane0s gather h into LDS; wave0 lanes 0-7
//  issue ONE coalesced 32B publish; wave0 polls out[ts] row with 16x8B
//  coalesced loads/lane, per-word retry, own-block words pre-seeded.
// =====================================================================

#define WDECL(g) f32x2 w##g##_0, w##g##_1, w##g##_2, w##g##_3, w##g##_4, \
  w##g##_5, w##g##_6, w##g##_7, w##g##_8, w##g##_9, w##g##_10, w##g##_11, \
  w##g##_12, w##g##_13, w##g##_14, w##g##_15;

#define WLOAD(g) do { \
  const float* wp = Whh + ((size_t)g * HDIM + j) * HDIM + lane * 4; \
  float4 q; \
  q = *(const float4*)(wp + 0*256); w##g##_0  = f32x2{q.x,q.y}; w##g##_1  = f32x2{q.z,q.w}; \
  q = *(const float4*)(wp + 1*256); w##g##_2  = f32x2{q.x,q.y}; w##g##_3  = f32x2{q.z,q.w}; \
  q = *(const float4*)(wp + 2*256); w##g##_4  = f32x2{q.x,q.y}; w##g##_5  = f32x2{q.z,q.w}; \
  q = *(const float4*)(wp + 3*256); w##g##_6  = f32x2{q.x,q.y}; w##g##_7  = f32x2{q.z,q.w}; \
  q = *(const float4*)(wp + 4*256); w##g##_8  = f32x2{q.x,q.y}; w##g##_9  = f32x2{q.z,q.w}; \
  q = *(const float4*)(wp + 5*256); w##g##_10 = f32x2{q.x,q.y}; w##g##_11 = f32x2{q.z,q.w}; \
  q = *(const float4*)(wp + 6*256); w##g##_12 = f32x2{q.x,q.y}; w##g##_13 = f32x2{q.z,q.w}; \
  q = *(const float4*)(wp + 7*256); w##g##_14 = f32x2{q.x,q.y}; w##g##_15 = f32x2{q.z,q.w}; \
} while (0)

#define DOTI(idx, p, q_) do { \
  const f32x4 hv = h4[idx * 64]; \
  const f32x2 hlo = {hv.x, hv.y}, hhi = {hv.z, hv.w}; \
  PKFMA(A0, w0_##p, hlo); PKFMA(A0, w0_##q_, hhi); \
  PKFMA(A1, w1_##p, hlo); PKFMA(A1, w1_##q_, hhi); \
  PKFMA(A2, w2_##p, hlo); PKFMA(A2, w2_##q_, hhi); \
  PKFMA(A3, w3_##p, hlo); PKFMA(A3, w3_##q_, hhi); \
} while (0)

#define POLL1(i) do { if (!(dn & (1u << i))) { \
  unsigned long long r = __hip_atomic_load(src + i * 64 + lane, \
      __ATOMIC_RELAXED, __HIP_MEMORY_SCOPE_AGENT); \
  if (((unsigned)r != SENT) & ((unsigned)(r >> 32) != SENT)) { \
    v##i = r; dn |= 1u << i; } } } while (0)

#define STAGE1(i) do { if (!(dn_init & (1u << i))) hq[i * 64 + lane] = v##i; } while (0)

__global__ __launch_bounds__(TPB, 1) void lstm_scan(
    const unsigned short* __restrict__ xg, const float* __restrict__ Whh,
    const float* __restrict__ h0, const float* __restrict__ c0,
    float* __restrict__ out) {
  __shared__ __align__(16) float h_sh[HDIM];
  __shared__ float h_out[8];

  const int b = blockIdx.x, t = threadIdx.x;
  const int lane = t & 63, wid = t >> 6;
  const int j = b * 8 + wid;                      // this wave's unit

  WDECL(0) WDECL(1) WDECL(2) WDECL(3)             // 128 VGPRs of weights
  WLOAD(0); WLOAD(1); WLOAD(2); WLOAD(3);

  float c_reg = (lane == 0) ? c0[j] : 0.f;
  const f32x4* h4 = (const f32x4*)&h_sh[lane * 4];
  unsigned long long* hq = (unsigned long long*)h_sh;

  // own-block u64 words (out[.., b*8..b*8+8) = u64 idx b*4..b*4+4):
  // pre-seeded from LDS, skipped in poll
  unsigned dn_init = 0;
#pragma unroll
  for (int i = 0; i < 16; ++i)
    if (i * 64 + lane >= b * 4 && i * 64 + lane < b * 4 + 4)
      dn_init |= 1u << i;

  // prologue: stage h0
  h_sh[t]        = h0[t];
  h_sh[t + 512]  = h0[t + 512];
  h_sh[t + 1024] = h0[t + 1024];
  h_sh[t + 1536] = h0[t + 1536];
  __syncthreads();

  for (int ts = 0; ts < S_LEN; ++ts) {
    // xg prefetch (lanes 0-3: this unit's 4 gate pre-activations)
    float xgv = 0.f;
    if (lane < 4)
      xgv = bf2f(xg[(size_t)ts * G4 + (size_t)lane * HDIM + j]);

    // ---- packed dot from LDS h (conflict-free b128 reads) ----
    f32x2 A0 = {0.f, 0.f}, A1 = {0.f, 0.f}, A2 = {0.f, 0.f}, A3 = {0.f, 0.f};
    DOTI(0, 0, 1);   DOTI(1, 2, 3);   DOTI(2, 4, 5);   DOTI(3, 6, 7);
    DOTI(4, 8, 9);   DOTI(5, 10, 11); DOTI(6, 12, 13); DOTI(7, 14, 15);

    float a0 = A0.x + A0.y, a1 = A1.x + A1.y;
    float a2 = A2.x + A2.y, a3 = A3.x + A3.y;
#pragma unroll
    for (int m = 1; m < 64; m <<= 1) {
      a0 += __shfl_xor(a0, m);
      a1 += __shfl_xor(a1, m);
      a2 += __shfl_xor(a2, m);
      a3 += __shfl_xor(a3, m);
    }
    float sv = (lane == 0) ? a0 : (lane == 1) ? a1 : (lane == 2) ? a2 : a3;
    sv += xgv;
    const float av = (lane == 2) ? tanh_fast(sv) : sigmoid_fast(sv);
    const float iv = __shfl(av, 0);
    const float fv = __shfl(av, 1);
    const float gv = __shfl(av, 2);
    const float ov = __shfl(av, 3);
    if (lane == 0) {
      c_reg = fmaf(fv, c_reg, iv * gv);
      h_out[wid] = ov * tanh_fast(c_reg);         // gather to LDS
    }
    __syncthreads();                              // BAR_A: h_out ready; h_sh free

    if (wid == 0) {
      // coalesced 32B publish (one wave, 8 lanes)
      if (lane < 8)
        __hip_atomic_store(&out[(size_t)ts * HDIM + b * 8 + lane], h_out[lane],
                           __ATOMIC_RELAXED, __HIP_MEMORY_SCOPE_AGENT);
      if (ts + 1 < S_LEN) {
        // seed own 8 values locally (skip self fabric RT)
        if (lane < 8) h_sh[b * 8 + lane] = h_out[lane];
        // poll h_ts row: 16x8B coalesced per lane, per-word retry
        const unsigned long long* src =
            (const unsigned long long*)(out + (size_t)ts * HDIM);
        unsigned long long v0, v1, v2, v3, v4, v5, v6, v7,
                           v8, v9, v10, v11, v12, v13, v14, v15;
        unsigned dn = dn_init;
        for (;;) {
          POLL1(0);  POLL1(1);  POLL1(2);  POLL1(3);
          POLL1(4);  POLL1(5);  POLL1(6);  POLL1(7);
          POLL1(8);  POLL1(9);  POLL1(10); POLL1(11);
          POLL1(12); POLL1(13); POLL1(14); POLL1(15);
          if (__all(dn == 0xFFFFu)) break;
          __builtin_amdgcn_s_sleep(2);
        }
        STAGE1(0);  STAGE1(1);  STAGE1(2);  STAGE1(3);
        STAGE1(4);  STAGE1(5);  STAGE1(6);  STAGE1(7);
        STAGE1(8);  STAGE1(9);  STAGE1(10); STAGE1(11);
        STAGE1(12); STAGE1(13); STAGE1(14); STAGE1(15);
      }
    }
    __syncthreads();                              // BAR_B: h_sh = h_ts ready
  }
}

// =====================================================================
extern "C" void kernel_launch(void* const* d_in, const int* in_sizes, int n_in,
                              void* d_out, int out_size, void* d_ws, size_t ws_size,
                              hipStream_t stream) {
  const float* x   = (const float*)d_in[0];
  const float* Wih = (const float*)d_in[1];
  const float* Whh = (const float*)d_in[2];
  const float* bih = (const float*)d_in[3];
  const float* bhh = (const float*)d_in[4];
  const float* h0  = (const float*)d_in[5];
  const float* c0  = (const float*)d_in[6];
  float* out = (float*)d_out;

  unsigned short* xg = (unsigned short*)d_ws;      // 64 MB bf16

  fill_sentinel<<<dim3(2048), 256, 0, stream>>>((unsigned long long*)out);
  gemm_xg_mfma<<<dim3(2048), 256, 0, stream>>>(x, Wih, bih, bhh, xg);

  void* args[] = {(void*)&xg, (void*)&Whh, (void*)&h0, (void*)&c0, (void*)&out};
  hipLaunchCooperativeKernel((void*)lstm_scan, dim3(NB), dim3(TPB),
                             args, 0, stream);
}

// Round 8
// 19139.326 us; speedup vs baseline: 1.5926x; 1.5926x over previous
//
#include <hip/hip_runtime.h>
#include <hip/hip_bf16.h>

#define S_LEN 4096
#define IDIM  2048
#define HDIM  2048
#define G4    8192
#define NB    256
#define TPB   512
#define SENT  0x7FC00000u   // qNaN: h = sigmoid*tanh of finite data, never NaN

typedef __attribute__((ext_vector_type(4))) float  f32x4;
typedef __attribute__((ext_vector_type(8))) short  bf16x8;

// ---- bf16 helpers ----
__device__ __forceinline__ unsigned short f2bf(float f) {
  unsigned u = __float_as_uint(f);
  unsigned r = (u + 0x7FFFu + ((u >> 16) & 1u)) >> 16;   // RNE
  return (unsigned short)r;
}
__device__ __forceinline__ float bf2f(unsigned short h) {
  return __uint_as_float(((unsigned)h) << 16);
}
__device__ __forceinline__ float sigmoid_fast(float x) {
  return __builtin_amdgcn_rcpf(1.f + __expf(-x));
}
__device__ __forceinline__ float tanh_fast(float x) {
  return 1.f - 2.f * __builtin_amdgcn_rcpf(__expf(2.f * x) + 1.f);
}

// =====================================================================
// Kernel 0: fill out with sentinel (per-element readiness ground state)
// =====================================================================
__global__ __launch_bounds__(256) void fill_sentinel(unsigned long long* p) {
  const unsigned long long v =
      ((unsigned long long)SENT << 32) | (unsigned long long)SENT;
  const int n = S_LEN * HDIM / 2;
  for (int i = blockIdx.x * 256 + threadIdx.x; i < n; i += gridDim.x * 256)
    p[i] = v;
}

// =====================================================================
// Kernel 1: xg = x·W_ihᵀ + b_ih + b_hh, bf16 MFMA. (proven, ~0.1 ms)
// =====================================================================
#define BM 128
#define BKK 32
#define LDK 40

__global__ __launch_bounds__(256) void gemm_xg_mfma(
    const float* __restrict__ x, const float* __restrict__ Wih,
    const float* __restrict__ bih, const float* __restrict__ bhh,
    unsigned short* __restrict__ xg) {
  __shared__ unsigned short As[BM][LDK];
  __shared__ unsigned short Bs[BM][LDK];

  const int t = threadIdx.x;
  const int lane = t & 63, wid = t >> 6;
  const int wr = wid >> 1, wc = wid & 1;

  int bid = ((int)blockIdx.x & 7) * 256 + ((int)blockIdx.x >> 3);
  const int s0 = (bid >> 6) * BM;
  const int j0 = (bid & 63) * BM;

  f32x4 acc[4][4] = {};

  float bias[4];
#pragma unroll
  for (int n = 0; n < 4; ++n) {
    const int col = j0 + wc * 64 + n * 16 + (lane & 15);
    bias[n] = bih[col] + bhh[col];
  }

  for (int k0 = 0; k0 < IDIM; k0 += BKK) {
    float4 va[4], vb[4];
#pragma unroll
    for (int u = 0; u < 4; ++u) {
      const int f = t + 256 * u;
      const int row = f >> 3, kc = (f & 7) * 4;
      va[u] = *(const float4*)&x  [(size_t)(s0 + row) * IDIM + k0 + kc];
      vb[u] = *(const float4*)&Wih[(size_t)(j0 + row) * IDIM + k0 + kc];
    }
    __syncthreads();
#pragma unroll
    for (int u = 0; u < 4; ++u) {
      const int f = t + 256 * u;
      const int row = f >> 3, kc = (f & 7) * 4;
      ushort4 pa, pb;
      pa.x = f2bf(va[u].x); pa.y = f2bf(va[u].y);
      pa.z = f2bf(va[u].z); pa.w = f2bf(va[u].w);
      pb.x = f2bf(vb[u].x); pb.y = f2bf(vb[u].y);
      pb.z = f2bf(vb[u].z); pb.w = f2bf(vb[u].w);
      *(ushort4*)&As[row][kc] = pa;
      *(ushort4*)&Bs[row][kc] = pb;
    }
    __syncthreads();

    const int fr = lane & 15, koff = (lane >> 4) * 8;
    bf16x8 a[4], bfr[4];
#pragma unroll
    for (int m = 0; m < 4; ++m)
      a[m] = *(const bf16x8*)&As[wr * 64 + m * 16 + fr][koff];
#pragma unroll
    for (int n = 0; n < 4; ++n)
      bfr[n] = *(const bf16x8*)&Bs[wc * 64 + n * 16 + fr][koff];
#pragma unroll
    for (int m = 0; m < 4; ++m)
#pragma unroll
      for (int n = 0; n < 4; ++n)
        acc[m][n] = __builtin_amdgcn_mfma_f32_16x16x32_bf16(
            a[m], bfr[n], acc[m][n], 0, 0, 0);
  }

#pragma unroll
  for (int m = 0; m < 4; ++m) {
    const int row0 = s0 + wr * 64 + m * 16 + (lane >> 4) * 4;
#pragma unroll
    for (int n = 0; n < 4; ++n) {
      const int col = j0 + wc * 64 + n * 16 + (lane & 15);
#pragma unroll
      for (int r = 0; r < 4; ++r)
        xg[(size_t)(row0 + r) * G4 + col] = f2bf(acc[m][n][r] + bias[n]);
    }
  }
}

// =====================================================================
// Kernel 2: persistent scan.
//  WEIGHTS: 128 fp32/thread pinned in AGPRs via v_accvgpr_write asm.
//  Rounds 1-7 post-mortem: plain loads of const __restrict__ weights get
//  REMATERIALIZED by hipcc (VGPR stayed 84-100 every round) — the dot
//  re-streamed 64MB/step from L2/L3 on the critical path. An asm result
//  cannot be rematerialized: residency is now structural.
//  SYNC: r6 structure (measured best): flag hint poll by wave0 +
//  sentinel-verified all-thread bulk read; raw s_barrier before flag
//  (no store-ack drain); per-element qNaN retry is the correctness net.
// =====================================================================

#define AWRITE(dst, src) \
  asm volatile("v_accvgpr_write_b32 %0, %1" : "=a"(dst) : "v"(src))
#define AFMA(acc, wa, hv) do { float _t; \
  asm("v_accvgpr_read_b32 %0, %1" : "=v"(_t) : "a"(wa)); \
  acc = fmaf(_t, hv, acc); } while (0)

#define AWN(g,i) wa##g##_##i##_0, wa##g##_##i##_1, wa##g##_##i##_2, wa##g##_##i##_3
#define WDECL(g) float AWN(g,0), AWN(g,1), AWN(g,2), AWN(g,3), \
                       AWN(g,4), AWN(g,5), AWN(g,6), AWN(g,7);

#define WLOAD1(g,i) do { \
  const float4 q = *(const float4*)(wp##g + i * 256); \
  AWRITE(wa##g##_##i##_0, q.x); AWRITE(wa##g##_##i##_1, q.y); \
  AWRITE(wa##g##_##i##_2, q.z); AWRITE(wa##g##_##i##_3, q.w); } while (0)

#define WLOAD(g) do { const float* wp##g = \
    Whh + ((size_t)g * HDIM + j) * HDIM + lane * 4; \
  WLOAD1(g,0); WLOAD1(g,1); WLOAD1(g,2); WLOAD1(g,3); \
  WLOAD1(g,4); WLOAD1(g,5); WLOAD1(g,6); WLOAD1(g,7); } while (0)

#define DOTI(i) do { \
  const f32x4 hv = h4[i * 64]; \
  AFMA(a0, wa0_##i##_0, hv.x); AFMA(a0, wa0_##i##_1, hv.y); \
  AFMA(a0, wa0_##i##_2, hv.z); AFMA(a0, wa0_##i##_3, hv.w); \
  AFMA(a1, wa1_##i##_0, hv.x); AFMA(a1, wa1_##i##_1, hv.y); \
  AFMA(a1, wa1_##i##_2, hv.z); AFMA(a1, wa1_##i##_3, hv.w); \
  AFMA(a2, wa2_##i##_0, hv.x); AFMA(a2, wa2_##i##_1, hv.y); \
  AFMA(a2, wa2_##i##_2, hv.z); AFMA(a2, wa2_##i##_3, hv.w); \
  AFMA(a3, wa3_##i##_0, hv.x); AFMA(a3, wa3_##i##_1, hv.y); \
  AFMA(a3, wa3_##i##_2, hv.z); AFMA(a3, wa3_##i##_3, hv.w); } while (0)

__global__ __launch_bounds__(TPB, 2) void lstm_scan(
    const unsigned short* __restrict__ xg, const float* __restrict__ Whh,
    const float* __restrict__ h0, const float* __restrict__ c0,
    float* __restrict__ out, unsigned* __restrict__ flags) {
  __shared__ __align__(16) float h_sh[HDIM];

  const int b = blockIdx.x, t = threadIdx.x;
  const int lane = t & 63, wid = t >> 6;
  const int j = b * 8 + wid;                      // this wave's unit

  WDECL(0) WDECL(1) WDECL(2) WDECL(3)             // 128 floats -> AGPRs
  WLOAD(0); WLOAD(1); WLOAD(2); WLOAD(3);

  float c_reg = (lane == 0) ? c0[j] : 0.f;
  const f32x4* h4 = (const f32x4*)&h_sh[lane * 4];

  // prologue: stage h0
  h_sh[t]        = h0[t];
  h_sh[t + 512]  = h0[t + 512];
  h_sh[t + 1024] = h0[t + 1024];
  h_sh[t + 1536] = h0[t + 1536];
  __syncthreads();

  for (int ts = 0; ts < S_LEN; ++ts) {
    // xg prefetch (lanes 0-3: this unit's 4 gate pre-activations)
    float xgv = 0.f;
    if (lane < 4)
      xgv = bf2f(xg[(size_t)ts * G4 + (size_t)lane * HDIM + j]);

    // ---- dot: 128 AGPR-resident MACs vs conflict-free b128 LDS reads ----
    float a0 = 0.f, a1 = 0.f, a2 = 0.f, a3 = 0.f;
    DOTI(0); DOTI(1); DOTI(2); DOTI(3);
    DOTI(4); DOTI(5); DOTI(6); DOTI(7);

#pragma unroll
    for (int m = 1; m < 64; m <<= 1) {
      a0 += __shfl_xor(a0, m);
      a1 += __shfl_xor(a1, m);
      a2 += __shfl_xor(a2, m);
      a3 += __shfl_xor(a3, m);
    }
    float sv = (lane == 0) ? a0 : (lane == 1) ? a1 : (lane == 2) ? a2 : a3;
    sv += xgv;
    const float av = (lane == 2) ? tanh_fast(sv) : sigmoid_fast(sv);
    const float iv = __shfl(av, 0);
    const float fv = __shfl(av, 1);
    const float gv = __shfl(av, 2);
    const float ov = __shfl(av, 3);
    if (lane == 0) {
      c_reg = fmaf(fv, c_reg, iv * gv);
      const float hn = ov * tanh_fast(c_reg);
      __hip_atomic_store(&out[(size_t)ts * HDIM + j], hn,
                         __ATOMIC_RELAXED, __HIP_MEMORY_SCOPE_AGENT);
    }
    // raw barrier: collect all waves' store-issue; NO vmcnt drain
    __builtin_amdgcn_s_barrier();
    if (t == 0)
      __hip_atomic_store(&flags[b], (unsigned)(ts + 1),
                         __ATOMIC_RELAXED, __HIP_MEMORY_SCOPE_AGENT);

    if (ts + 1 == S_LEN) break;

    // ---- wave0: poll 256 hint-flags (1 KB; reload only missing) ----
    if (wid == 0) {
      const unsigned want = (unsigned)(ts + 1);
      unsigned f0 = 0, f1 = 0, f2 = 0, f3 = 0;
      for (;;) {
        if (f0 < want) f0 = __hip_atomic_load(&flags[lane],       __ATOMIC_RELAXED, __HIP_MEMORY_SCOPE_AGENT);
        if (f1 < want) f1 = __hip_atomic_load(&flags[lane +  64], __ATOMIC_RELAXED, __HIP_MEMORY_SCOPE_AGENT);
        if (f2 < want) f2 = __hip_atomic_load(&flags[lane + 128], __ATOMIC_RELAXED, __HIP_MEMORY_SCOPE_AGENT);
        if (f3 < want) f3 = __hip_atomic_load(&flags[lane + 192], __ATOMIC_RELAXED, __HIP_MEMORY_SCOPE_AGENT);
        if (f0 >= want && f1 >= want && f2 >= want && f3 >= want) break;
        __builtin_amdgcn_s_sleep(1);
      }
    }
    __syncthreads();                   // hint seen; h_sh free (s_barrier above
                                       // already fenced all waves' dot reads)
    // ---- bulk read h_ts: 2x8B/thread, per-element sentinel retry ----
    const unsigned long long* src =
        (const unsigned long long*)(out + (size_t)ts * HDIM);
    unsigned long long r0, r1;
    do {
      r0 = __hip_atomic_load(src + t, __ATOMIC_RELAXED,
                             __HIP_MEMORY_SCOPE_AGENT);
    } while (((unsigned)r0 == SENT) | ((unsigned)(r0 >> 32) == SENT));
    do {
      r1 = __hip_atomic_load(src + t + 512, __ATOMIC_RELAXED,
                             __HIP_MEMORY_SCOPE_AGENT);
    } while (((unsigned)r1 == SENT) | ((unsigned)(r1 >> 32) == SENT));
    h_sh[2*t]        = __uint_as_float((unsigned)r0);
    h_sh[2*t + 1]    = __uint_as_float((unsigned)(r0 >> 32));
    h_sh[2*t + 1024] = __uint_as_float((unsigned)r1);
    h_sh[2*t + 1025] = __uint_as_float((unsigned)(r1 >> 32));
    __syncthreads();                   // h_sh = h_ts ready
  }
}

// =====================================================================
extern "C" void kernel_launch(void* const* d_in, const int* in_sizes, int n_in,
                              void* d_out, int out_size, void* d_ws, size_t ws_size,
                              hipStream_t stream) {
  const float* x   = (const float*)d_in[0];
  const float* Wih = (const float*)d_in[1];
  const float* Whh = (const float*)d_in[2];
  const float* bih = (const float*)d_in[3];
  const float* bhh = (const float*)d_in[4];
  const float* h0  = (const float*)d_in[5];
  const float* c0  = (const float*)d_in[6];
  float* out = (float*)d_out;

  // ws layout: [0,1KB) flags | [32KB, +64MB) xg bf16
  unsigned* flags = (unsigned*)d_ws;
  unsigned short* xg = (unsigned short*)((char*)d_ws + 32768);

  hipMemsetAsync(flags, 0, NB * sizeof(unsigned), stream);

  fill_sentinel<<<dim3(2048), 256, 0, stream>>>((unsigned long long*)out);
  gemm_xg_mfma<<<dim3(2048), 256, 0, stream>>>(x, Wih, bih, bhh, xg);

  void* args[] = {(void*)&xg, (void*)&Whh, (void*)&h0,
                  (void*)&c0, (void*)&out, (void*)&flags};
  hipLaunchCooperativeKernel((void*)lstm_scan, dim3(NB), dim3(TPB),
                             args, 0, stream);
}

// Round 9
// 18891.808 us; speedup vs baseline: 1.6135x; 1.0131x over previous
//
#include <hip/hip_runtime.h>
#include <hip/hip_bf16.h>

#define S_LEN 4096
#define IDIM  2048
#define HDIM  2048
#define G4    8192
#define NB    256
#define TPB   512
#define SENT  0x7FC00000u   // qNaN: h = sigmoid*tanh of finite data, never NaN

typedef __attribute__((ext_vector_type(2))) float  f32x2;
typedef __attribute__((ext_vector_type(4))) float  f32x4;
typedef __attribute__((ext_vector_type(8))) short  bf16x8;

// packed fp32 FMA: acc += w*h (2 MACs/instruction)
#define PKFMA(acc, w, h) \
  asm("v_pk_fma_f32 %0, %1, %2, %0" : "+v"(acc) : "v"(w), "v"(h))

// ---- bf16 helpers ----
__device__ __forceinline__ unsigned short f2bf(float f) {
  unsigned u = __float_as_uint(f);
  unsigned r = (u + 0x7FFFu + ((u >> 16) & 1u)) >> 16;   // RNE
  return (unsigned short)r;
}
__device__ __forceinline__ float bf2f(unsigned short h) {
  return __uint_as_float(((unsigned)h) << 16);
}
// unpack 2 packed bf16 -> f32x2 (2 VALU: shift, and)
__device__ __forceinline__ f32x2 bfpair(unsigned u) {
  f32x2 r;
  r.x = __uint_as_float(u << 16);
  r.y = __uint_as_float(u & 0xFFFF0000u);
  return r;
}
__device__ __forceinline__ f32x2 mk2(float a, float b) {
  f32x2 r; r.x = a; r.y = b; return r;
}
__device__ __forceinline__ float sigmoid_fast(float x) {
  return __builtin_amdgcn_rcpf(1.f + __expf(-x));
}
__device__ __forceinline__ float tanh_fast(float x) {
  return 1.f - 2.f * __builtin_amdgcn_rcpf(__expf(2.f * x) + 1.f);
}

// =====================================================================
// Kernel 0: fill out with sentinel (per-element readiness ground state)
// =====================================================================
__global__ __launch_bounds__(256) void fill_sentinel(unsigned long long* p) {
  const unsigned long long v =
      ((unsigned long long)SENT << 32) | (unsigned long long)SENT;
  const int n = S_LEN * HDIM / 2;
  for (int i = blockIdx.x * 256 + threadIdx.x; i < n; i += gridDim.x * 256)
    p[i] = v;
}

// =====================================================================
// Kernel 1: xg = x·W_ihᵀ + b_ih + b_hh, bf16 MFMA. (proven, ~0.1 ms)
// =====================================================================
#define BM 128
#define BKK 32
#define LDK 40

__global__ __launch_bounds__(256) void gemm_xg_mfma(
    const float* __restrict__ x, const float* __restrict__ Wih,
    const float* __restrict__ bih, const float* __restrict__ bhh,
    unsigned short* __restrict__ xg) {
  __shared__ unsigned short As[BM][LDK];
  __shared__ unsigned short Bs[BM][LDK];

  const int t = threadIdx.x;
  const int lane = t & 63, wid = t >> 6;
  const int wr = wid >> 1, wc = wid & 1;

  int bid = ((int)blockIdx.x & 7) * 256 + ((int)blockIdx.x >> 3);
  const int s0 = (bid >> 6) * BM;
  const int j0 = (bid & 63) * BM;

  f32x4 acc[4][4] = {};

  float bias[4];
#pragma unroll
  for (int n = 0; n < 4; ++n) {
    const int col = j0 + wc * 64 + n * 16 + (lane & 15);
    bias[n] = bih[col] + bhh[col];
  }

  for (int k0 = 0; k0 < IDIM; k0 += BKK) {
    float4 va[4], vb[4];
#pragma unroll
    for (int u = 0; u < 4; ++u) {
      const int f = t + 256 * u;
      const int row = f >> 3, kc = (f & 7) * 4;
      va[u] = *(const float4*)&x  [(size_t)(s0 + row) * IDIM + k0 + kc];
      vb[u] = *(const float4*)&Wih[(size_t)(j0 + row) * IDIM + k0 + kc];
    }
    __syncthreads();
#pragma unroll
    for (int u = 0; u < 4; ++u) {
      const int f = t + 256 * u;
      const int row = f >> 3, kc = (f & 7) * 4;
      ushort4 pa, pb;
      pa.x = f2bf(va[u].x); pa.y = f2bf(va[u].y);
      pa.z = f2bf(va[u].z); pa.w = f2bf(va[u].w);
      pb.x = f2bf(vb[u].x); pb.y = f2bf(vb[u].y);
      pb.z = f2bf(vb[u].z); pb.w = f2bf(vb[u].w);
      *(ushort4*)&As[row][kc] = pa;
      *(ushort4*)&Bs[row][kc] = pb;
    }
    __syncthreads();

    const int fr = lane & 15, koff = (lane >> 4) * 8;
    bf16x8 a[4], bfr[4];
#pragma unroll
    for (int m = 0; m < 4; ++m)
      a[m] = *(const bf16x8*)&As[wr * 64 + m * 16 + fr][koff];
#pragma unroll
    for (int n = 0; n < 4; ++n)
      bfr[n] = *(const bf16x8*)&Bs[wc * 64 + n * 16 + fr][koff];
#pragma unroll
    for (int m = 0; m < 4; ++m)
#pragma unroll
      for (int n = 0; n < 4; ++n)
        acc[m][n] = __builtin_amdgcn_mfma_f32_16x16x32_bf16(
            a[m], bfr[n], acc[m][n], 0, 0, 0);
  }

#pragma unroll
  for (int m = 0; m < 4; ++m) {
    const int row0 = s0 + wr * 64 + m * 16 + (lane >> 4) * 4;
#pragma unroll
    for (int n = 0; n < 4; ++n) {
      const int col = j0 + wc * 64 + n * 16 + (lane & 15);
#pragma unroll
      for (int r = 0; r < 4; ++r)
        xg[(size_t)(row0 + r) * G4 + col] = f2bf(acc[m][n][r] + bias[n]);
    }
  }
}

// =====================================================================
// Kernel 2: persistent scan.
//  WEIGHTS: lane's 128 weights as 64 packed-bf16 dwords in VGPRs, each
//  pinned with asm volatile("" : "+v") — a volatile asm result cannot be
//  rematerialized, so hipcc cannot re-issue the global loads per step
//  (r1-r7 failure); unpack at use is plain shl/and + v_pk_fma (no per-use
//  asm — the r8 failure). Residency assert: VGPR_Count must be >=140.
//  h: LDS, de-interleaved hA/hB so all ds_read_b128 are lane-contiguous.
//  SYNC: r6 structure (measured best ~1.0us): raw s_barrier -> flag hint;
//  wave0 polls 256 flags; all threads bulk-read with qNaN sentinel retry.
// =====================================================================

// lane l, chunk c covers k = c*512 + l*8 + e (e=0..7); hA holds e<4, hB e>=4
__device__ __forceinline__ void stage_pair(float* hA, float* hB, int k,
                                           float v0, float v1) {
  const int c = k >> 9, r = (k >> 3) & 63, e = k & 7;
  float* dst = ((e & 4) ? hB : hA) + c * 256 + r * 4 + (e & 3);
  dst[0] = v0;
  dst[1] = v1;
}

// one (gate g, chunk c) contribution: uint4 wv = 8 bf16, vs ha/hb f32x4
#define DGC(Acc, g, c, HA, HB) do {                       \
  const uint4 wv = w_reg[(g) * 4 + (c)];                  \
  PKFMA(Acc, bfpair(wv.x), mk2(HA.x, HA.y));              \
  PKFMA(Acc, bfpair(wv.y), mk2(HA.z, HA.w));              \
  PKFMA(Acc, bfpair(wv.z), mk2(HB.x, HB.y));              \
  PKFMA(Acc, bfpair(wv.w), mk2(HB.z, HB.w));              \
} while (0)

__global__ __launch_bounds__(TPB, 2) void lstm_scan(
    const unsigned short* __restrict__ xg, const float* __restrict__ Whh,
    const float* __restrict__ h0, const float* __restrict__ c0,
    float* __restrict__ out, unsigned* __restrict__ flags) {
  __shared__ __align__(16) float hA[1024];   // e in 0..3 of each 8-k granule
  __shared__ __align__(16) float hB[1024];   // e in 4..7

  const int b = blockIdx.x, t = threadIdx.x;
  const int lane = t & 63, wid = t >> 6;
  const int j = b * 8 + wid;                 // this wave's unit

  // ---- one-time: weights -> 64 packed-bf16 dwords, asm-pinned ----
  uint4 w_reg[16];
#pragma unroll
  for (int g = 0; g < 4; ++g) {
    const float* wp = Whh + ((size_t)g * HDIM + j) * HDIM;
#pragma unroll
    for (int c = 0; c < 4; ++c) {
      const float4 q0 = *(const float4*)(wp + c * 512 + lane * 8);
      const float4 q1 = *(const float4*)(wp + c * 512 + lane * 8 + 4);
      uint4 pk;
      pk.x = (unsigned)f2bf(q0.x) | ((unsigned)f2bf(q0.y) << 16);
      pk.y = (unsigned)f2bf(q0.z) | ((unsigned)f2bf(q0.w) << 16);
      pk.z = (unsigned)f2bf(q1.x) | ((unsigned)f2bf(q1.y) << 16);
      pk.w = (unsigned)f2bf(q1.z) | ((unsigned)f2bf(q1.w) << 16);
      asm volatile("" : "+v"(pk.x), "+v"(pk.y), "+v"(pk.z), "+v"(pk.w));
      w_reg[g * 4 + c] = pk;
    }
  }

  float c_reg = (lane == 0) ? c0[j] : 0.f;

  // stage h0 into hA/hB
  {
    const float2 p0 = *(const float2*)&h0[2 * t];
    const float2 p1 = *(const float2*)&h0[2 * t + 1024];
    stage_pair(hA, hB, 2 * t, p0.x, p0.y);
    stage_pair(hA, hB, 2 * t + 1024, p1.x, p1.y);
  }
  __syncthreads();

  for (int ts = 0; ts < S_LEN; ++ts) {
    // xg prefetch (lanes 0-3: this unit's 4 gate pre-activations)
    float xgv = 0.f;
    if (lane < 4)
      xgv = bf2f(xg[(size_t)ts * G4 + (size_t)lane * HDIM + j]);

    // ---- h LDS reads: 8 lane-contiguous b128 ----
    const f32x4 ha0 = *(const f32x4*)&hA[0 * 256 + lane * 4];
    const f32x4 ha1 = *(const f32x4*)&hA[1 * 256 + lane * 4];
    const f32x4 ha2 = *(const f32x4*)&hA[2 * 256 + lane * 4];
    const f32x4 ha3 = *(const f32x4*)&hA[3 * 256 + lane * 4];
    const f32x4 hb0 = *(const f32x4*)&hB[0 * 256 + lane * 4];
    const f32x4 hb1 = *(const f32x4*)&hB[1 * 256 + lane * 4];
    const f32x4 hb2 = *(const f32x4*)&hB[2 * 256 + lane * 4];
    const f32x4 hb3 = *(const f32x4*)&hB[3 * 256 + lane * 4];

    // ---- dot: 128 bf16-unpack + 64 v_pk_fma_f32 ----
    f32x2 A0 = {0.f, 0.f}, A1 = {0.f, 0.f}, A2 = {0.f, 0.f}, A3 = {0.f, 0.f};
    DGC(A0, 0, 0, ha0, hb0); DGC(A0, 0, 1, ha1, hb1);
    DGC(A0, 0, 2, ha2, hb2); DGC(A0, 0, 3, ha3, hb3);
    DGC(A1, 1, 0, ha0, hb0); DGC(A1, 1, 1, ha1, hb1);
    DGC(A1, 1, 2, ha2, hb2); DGC(A1, 1, 3, ha3, hb3);
    DGC(A2, 2, 0, ha0, hb0); DGC(A2, 2, 1, ha1, hb1);
    DGC(A2, 2, 2, ha2, hb2); DGC(A2, 2, 3, ha3, hb3);
    DGC(A3, 3, 0, ha0, hb0); DGC(A3, 3, 1, ha1, hb1);
    DGC(A3, 3, 2, ha2, hb2); DGC(A3, 3, 3, ha3, hb3);

    float a0 = A0.x + A0.y, a1 = A1.x + A1.y;
    float a2 = A2.x + A2.y, a3 = A3.x + A3.y;
#pragma unroll
    for (int m = 1; m < 64; m <<= 1) {
      a0 += __shfl_xor(a0, m);
      a1 += __shfl_xor(a1, m);
      a2 += __shfl_xor(a2, m);
      a3 += __shfl_xor(a3, m);
    }
    float sv = (lane == 0) ? a0 : (lane == 1) ? a1 : (lane == 2) ? a2 : a3;
    sv += xgv;
    const float av = (lane == 2) ? tanh_fast(sv) : sigmoid_fast(sv);
    const float iv = __shfl(av, 0);
    const float fv = __shfl(av, 1);
    const float gv = __shfl(av, 2);
    const float ov = __shfl(av, 3);
    if (lane == 0) {
      c_reg = fmaf(fv, c_reg, iv * gv);
      const float hn = ov * tanh_fast(c_reg);
      __hip_atomic_store(&out[(size_t)ts * HDIM + j], hn,
                         __ATOMIC_RELAXED, __HIP_MEMORY_SCOPE_AGENT);
    }
    // raw barrier (no vmcnt drain); then flag hint
    __builtin_amdgcn_s_barrier();
    if (t == 0)
      __hip_atomic_store(&flags[b], (unsigned)(ts + 1),
                         __ATOMIC_RELAXED, __HIP_MEMORY_SCOPE_AGENT);

    if (ts + 1 == S_LEN) break;

    // ---- wave0: poll 256 hint-flags (1 KB; reload only missing) ----
    if (wid == 0) {
      const unsigned want = (unsigned)(ts + 1);
      unsigned f0 = 0, f1 = 0, f2 = 0, f3 = 0;
      for (;;) {
        if (f0 < want) f0 = __hip_atomic_load(&flags[lane],       __ATOMIC_RELAXED, __HIP_MEMORY_SCOPE_AGENT);
        if (f1 < want) f1 = __hip_atomic_load(&flags[lane +  64], __ATOMIC_RELAXED, __HIP_MEMORY_SCOPE_AGENT);
        if (f2 < want) f2 = __hip_atomic_load(&flags[lane + 128], __ATOMIC_RELAXED, __HIP_MEMORY_SCOPE_AGENT);
        if (f3 < want) f3 = __hip_atomic_load(&flags[lane + 192], __ATOMIC_RELAXED, __HIP_MEMORY_SCOPE_AGENT);
        if (f0 >= want && f1 >= want && f2 >= want && f3 >= want) break;
        __builtin_amdgcn_s_sleep(1);
      }
    }
    __syncthreads();           // hint seen; all waves past dot -> hA/hB free
    // ---- bulk read h_ts: 2x8B/thread, per-element sentinel retry ----
    const unsigned long long* src =
        (const unsigned long long*)(out + (size_t)ts * HDIM);
    unsigned long long r0, r1;
    do {
      r0 = __hip_atomic_load(src + t, __ATOMIC_RELAXED,
                             __HIP_MEMORY_SCOPE_AGENT);
    } while (((unsigned)r0 == SENT) | ((unsigned)(r0 >> 32) == SENT));
    do {
      r1 = __hip_atomic_load(src + t + 512, __ATOMIC_RELAXED,
                             __HIP_MEMORY_SCOPE_AGENT);
    } while (((unsigned)r1 == SENT) | ((unsigned)(r1 >> 32) == SENT));
    stage_pair(hA, hB, 2 * t,
               __uint_as_float((unsigned)r0), __uint_as_float((unsigned)(r0 >> 32)));
    stage_pair(hA, hB, 2 * t + 1024,
               __uint_as_float((unsigned)r1), __uint_as_float((unsigned)(r1 >> 32)));
    __syncthreads();           // hA/hB = h_ts ready
  }
}

// =====================================================================
extern "C" void kernel_launch(void* const* d_in, const int* in_sizes, int n_in,
                              void* d_out, int out_size, void* d_ws, size_t ws_size,
                              hipStream_t stream) {
  const float* x   = (const float*)d_in[0];
  const float* Wih = (const float*)d_in[1];
  const float* Whh = (const float*)d_in[2];
  const float* bih = (const float*)d_in[3];
  const float* bhh = (const float*)d_in[4];
  const float* h0  = (const float*)d_in[5];
  const float* c0  = (const float*)d_in[6];
  float* out = (float*)d_out;

  // ws layout: [0,1KB) flags | [32KB, +64MB) xg bf16
  unsigned* flags = (unsigned*)d_ws;
  unsigned short* xg = (unsigned short*)((char*)d_ws + 32768);

  hipMemsetAsync(flags, 0, NB * sizeof(unsigned), stream);

  fill_sentinel<<<dim3(2048), 256, 0, stream>>>((unsigned long long*)out);
  gemm_xg_mfma<<<dim3(2048), 256, 0, stream>>>(x, Wih, bih, bhh, xg);

  void* args[] = {(void*)&xg, (void*)&Whh, (void*)&h0,
                  (void*)&c0, (void*)&out, (void*)&flags};
  hipLaunchCooperativeKernel((void*)lstm_scan, dim3(NB), dim3(TPB),
                             args, 0, stream);
}

// Round 10
// 16956.560 us; speedup vs baseline: 1.7976x; 1.1141x over previous
//
#include <hip/hip_runtime.h>
#include <hip/hip_bf16.h>

#define S_LEN 4096
#define IDIM  2048
#define HDIM  2048
#define G4    8192
#define NB    256
#define TPB   512
#define SENT  0x7FC00000u   // qNaN: h = sigmoid*tanh of finite data, never NaN

typedef __attribute__((ext_vector_type(2))) float  f32x2;
typedef __attribute__((ext_vector_type(4))) float  f32x4;
typedef __attribute__((ext_vector_type(8))) short  bf16x8;

// packed fp32 FMA: acc += w*h (2 MACs/instruction)
#define PKFMA(acc, w, h) \
  asm("v_pk_fma_f32 %0, %1, %2, %0" : "+v"(acc) : "v"(w), "v"(h))

// ---- bf16 helpers ----
__device__ __forceinline__ unsigned short f2bf(float f) {
  unsigned u = __float_as_uint(f);
  unsigned r = (u + 0x7FFFu + ((u >> 16) & 1u)) >> 16;   // RNE
  return (unsigned short)r;
}
__device__ __forceinline__ float bf2f(unsigned short h) {
  return __uint_as_float(((unsigned)h) << 16);
}
__device__ __forceinline__ f32x2 bfpair(unsigned u) {    // 2 packed bf16 -> f32x2
  f32x2 r;
  r.x = __uint_as_float(u << 16);
  r.y = __uint_as_float(u & 0xFFFF0000u);
  return r;
}
__device__ __forceinline__ f32x2 mk2(float a, float b) {
  f32x2 r; r.x = a; r.y = b; return r;
}
__device__ __forceinline__ float sigmoid_fast(float x) {
  return __builtin_amdgcn_rcpf(1.f + __expf(-x));
}
__device__ __forceinline__ float tanh_fast(float x) {
  return 1.f - 2.f * __builtin_amdgcn_rcpf(__expf(2.f * x) + 1.f);
}

// =====================================================================
// Kernel 0: fill out with sentinel (per-element readiness ground state)
// =====================================================================
__global__ __launch_bounds__(256) void fill_sentinel(unsigned long long* p) {
  const unsigned long long v =
      ((unsigned long long)SENT << 32) | (unsigned long long)SENT;
  const int n = S_LEN * HDIM / 2;
  for (int i = blockIdx.x * 256 + threadIdx.x; i < n; i += gridDim.x * 256)
    p[i] = v;
}

// =====================================================================
// Kernel 1: xg = x·W_ihᵀ + b_ih + b_hh, bf16 MFMA. (proven, ~0.1 ms)
// =====================================================================
#define BM 128
#define BKK 32
#define LDK 40

__global__ __launch_bounds__(256) void gemm_xg_mfma(
    const float* __restrict__ x, const float* __restrict__ Wih,
    const float* __restrict__ bih, const float* __restrict__ bhh,
    unsigned short* __restrict__ xg) {
  __shared__ unsigned short As[BM][LDK];
  __shared__ unsigned short Bs[BM][LDK];

  const int t = threadIdx.x;
  const int lane = t & 63, wid = t >> 6;
  const int wr = wid >> 1, wc = wid & 1;

  int bid = ((int)blockIdx.x & 7) * 256 + ((int)blockIdx.x >> 3);
  const int s0 = (bid >> 6) * BM;
  const int j0 = (bid & 63) * BM;

  f32x4 acc[4][4] = {};

  float bias[4];
#pragma unroll
  for (int n = 0; n < 4; ++n) {
    const int col = j0 + wc * 64 + n * 16 + (lane & 15);
    bias[n] = bih[col] + bhh[col];
  }

  for (int k0 = 0; k0 < IDIM; k0 += BKK) {
    float4 va[4], vb[4];
#pragma unroll
    for (int u = 0; u < 4; ++u) {
      const int f = t + 256 * u;
      const int row = f >> 3, kc = (f & 7) * 4;
      va[u] = *(const float4*)&x  [(size_t)(s0 + row) * IDIM + k0 + kc];
      vb[u] = *(const float4*)&Wih[(size_t)(j0 + row) * IDIM + k0 + kc];
    }
    __syncthreads();
#pragma unroll
    for (int u = 0; u < 4; ++u) {
      const int f = t + 256 * u;
      const int row = f >> 3, kc = (f & 7) * 4;
      ushort4 pa, pb;
      pa.x = f2bf(va[u].x); pa.y = f2bf(va[u].y);
      pa.z = f2bf(va[u].z); pa.w = f2bf(va[u].w);
      pb.x = f2bf(vb[u].x); pb.y = f2bf(vb[u].y);
      pb.z = f2bf(vb[u].z); pb.w = f2bf(vb[u].w);
      *(ushort4*)&As[row][kc] = pa;
      *(ushort4*)&Bs[row][kc] = pb;
    }
    __syncthreads();

    const int fr = lane & 15, koff = (lane >> 4) * 8;
    bf16x8 a[4], bfr[4];
#pragma unroll
    for (int m = 0; m < 4; ++m)
      a[m] = *(const bf16x8*)&As[wr * 64 + m * 16 + fr][koff];
#pragma unroll
    for (int n = 0; n < 4; ++n)
      bfr[n] = *(const bf16x8*)&Bs[wc * 64 + n * 16 + fr][koff];
#pragma unroll
    for (int m = 0; m < 4; ++m)
#pragma unroll
      for (int n = 0; n < 4; ++n)
        acc[m][n] = __builtin_amdgcn_mfma_f32_16x16x32_bf16(
            a[m], bfr[n], acc[m][n], 0, 0, 0);
  }

#pragma unroll
  for (int m = 0; m < 4; ++m) {
    const int row0 = s0 + wr * 64 + m * 16 + (lane >> 4) * 4;
#pragma unroll
    for (int n = 0; n < 4; ++n) {
      const int col = j0 + wc * 64 + n * 16 + (lane & 15);
#pragma unroll
      for (int r = 0; r < 4; ++r)
        xg[(size_t)(row0 + r) * G4 + col] = f2bf(acc[m][n][r] + bias[n]);
    }
  }
}

// =====================================================================
// Kernel 2: persistent scan — weights in LDS (the r1-r9 lesson: hipcc
// will NOT keep a per-thread weight cache in VGPRs across this loop;
// LDS residency is structural, not allocator-discretionary).
//  Wlds[128KB]: unit-gate row ug = wid*4+g (4096B each); lane l's 8-bf16
//  chunk for k-granule i at ushort idx ug*2048 + i*512 + l*8 —
//  ds_read_b128 lane-contiguous, conflict-free.
//  k-mapping: lane l covers k = i*512 + 8l + e; h de-interleaved into
//  hA (e<4) / hB (e>=4) so h reads are lane-contiguous b128 too.
//  PIPELINE: w-reads for step ts+1 issue right after ts's publish —
//  they complete during the flag-poll window (dead time otherwise).
//  SYNC: r6 structure (measured best): raw s_barrier -> flag store;
//  wave0 polls 256 flags; bulk h read with per-element qNaN retry.
// =====================================================================

#define DGC(Acc, g, i) do {                               \
  const uint4 wv = wr_[(g) * 4 + (i)];                    \
  PKFMA(Acc, bfpair(wv.x), mk2(ha[i].x, ha[i].y));        \
  PKFMA(Acc, bfpair(wv.y), mk2(ha[i].z, ha[i].w));        \
  PKFMA(Acc, bfpair(wv.z), mk2(hb[i].x, hb[i].y));        \
  PKFMA(Acc, bfpair(wv.w), mk2(hb[i].z, hb[i].w));        \
} while (0)

__global__ __launch_bounds__(TPB, 2) void lstm_scan(
    const unsigned short* __restrict__ xg, const float* __restrict__ Whh,
    const float* __restrict__ h0, const float* __restrict__ c0,
    float* __restrict__ out, unsigned* __restrict__ flags) {
  extern __shared__ unsigned short Wlds[];    // 65536 ushorts = 128 KB dynamic
  __shared__ __align__(16) float hA[1024];    // e in 0..3 of each 8-k granule
  __shared__ __align__(16) float hB[1024];    // e in 4..7

  const int b = blockIdx.x, t = threadIdx.x;
  const int lane = t & 63, wid = t >> 6;
  const int j = b * 8 + wid;                  // this wave's unit

  // ---- one-time: weights -> LDS (bf16), each thread its own slice ----
#pragma unroll
  for (int g = 0; g < 4; ++g) {
    const float* wp = Whh + ((size_t)g * HDIM + j) * HDIM;
#pragma unroll
    for (int i = 0; i < 4; ++i) {
      const float4 q0 = *(const float4*)(wp + i * 512 + lane * 8);
      const float4 q1 = *(const float4*)(wp + i * 512 + lane * 8 + 4);
      uint4 pk;
      pk.x = (unsigned)f2bf(q0.x) | ((unsigned)f2bf(q0.y) << 16);
      pk.y = (unsigned)f2bf(q0.z) | ((unsigned)f2bf(q0.w) << 16);
      pk.z = (unsigned)f2bf(q1.x) | ((unsigned)f2bf(q1.y) << 16);
      pk.w = (unsigned)f2bf(q1.z) | ((unsigned)f2bf(q1.w) << 16);
      *(uint4*)&Wlds[(wid * 4 + g) * 2048 + i * 512 + lane * 8] = pk;
    }
  }

  float c_reg = (lane == 0) ? c0[j] : 0.f;

  // stage h0 into hA/hB:  k = i*512 + 8l + e -> hA/hB[i*256 + l*4 + (e&3)]
  {
#pragma unroll
    for (int kk = 0; kk < 4; ++kk) {
      const int k = t + kk * 512;             // one fp32 per thread per chunk
      const float v = h0[k];
      const int i = k >> 9, r = (k >> 3) & 63, e = k & 7;
      (((e & 4) ? hB : hA) + i * 256 + r * 4)[e & 3] = v;
    }
  }
  __syncthreads();                            // weights + h0 staged

  // ---- prologue w-prefetch for step 0 ----
  uint4 wr_[16];
#pragma unroll
  for (int g = 0; g < 4; ++g)
#pragma unroll
    for (int i = 0; i < 4; ++i)
      wr_[g * 4 + i] =
          *(const uint4*)&Wlds[(wid * 4 + g) * 2048 + i * 512 + lane * 8];

  for (int ts = 0; ts < S_LEN; ++ts) {
    // xg prefetch (lanes 0-3: this unit's 4 gate pre-activations)
    float xgv = 0.f;
    if (lane < 4)
      xgv = bf2f(xg[(size_t)ts * G4 + (size_t)lane * HDIM + j]);

    // ---- h reads: 8 lane-contiguous b128 ----
    f32x4 ha[4], hb[4];
#pragma unroll
    for (int i = 0; i < 4; ++i) {
      ha[i] = *(const f32x4*)&hA[i * 256 + lane * 4];
      hb[i] = *(const f32x4*)&hB[i * 256 + lane * 4];
    }

    // ---- dot: 64 pk_fma + 128 unpack, weights from prefetched regs ----
    f32x2 A0 = {0.f, 0.f}, A1 = {0.f, 0.f}, A2 = {0.f, 0.f}, A3 = {0.f, 0.f};
    DGC(A0, 0, 0); DGC(A0, 0, 1); DGC(A0, 0, 2); DGC(A0, 0, 3);
    DGC(A1, 1, 0); DGC(A1, 1, 1); DGC(A1, 1, 2); DGC(A1, 1, 3);
    DGC(A2, 2, 0); DGC(A2, 2, 1); DGC(A2, 2, 2); DGC(A2, 2, 3);
    DGC(A3, 3, 0); DGC(A3, 3, 1); DGC(A3, 3, 2); DGC(A3, 3, 3);

    float a0 = A0.x + A0.y, a1 = A1.x + A1.y;
    float a2 = A2.x + A2.y, a3 = A3.x + A3.y;
#pragma unroll
    for (int m = 1; m < 64; m <<= 1) {
      a0 += __shfl_xor(a0, m);
      a1 += __shfl_xor(a1, m);
      a2 += __shfl_xor(a2, m);
      a3 += __shfl_xor(a3, m);
    }
    float sv = (lane == 0) ? a0 : (lane == 1) ? a1 : (lane == 2) ? a2 : a3;
    sv += xgv;
    const float av = (lane == 2) ? tanh_fast(sv) : sigmoid_fast(sv);
    const float iv = __shfl(av, 0);
    const float fv = __shfl(av, 1);
    const float gv = __shfl(av, 2);
    const float ov = __shfl(av, 3);
    if (lane == 0) {
      c_reg = fmaf(fv, c_reg, iv * gv);
      const float hn = ov * tanh_fast(c_reg);
      __hip_atomic_store(&out[(size_t)ts * HDIM + j], hn,
                         __ATOMIC_RELAXED, __HIP_MEMORY_SCOPE_AGENT);
    }
    // raw barrier (no vmcnt drain); then flag hint
    __builtin_amdgcn_s_barrier();
    if (t == 0)
      __hip_atomic_store(&flags[b], (unsigned)(ts + 1),
                         __ATOMIC_RELAXED, __HIP_MEMORY_SCOPE_AGENT);

    if (ts + 1 == S_LEN) break;

    // ---- w-prefetch for ts+1: LDS reads issue now, complete under poll ----
#pragma unroll
    for (int g = 0; g < 4; ++g)
#pragma unroll
      for (int i = 0; i < 4; ++i)
        wr_[g * 4 + i] =
            *(const uint4*)&Wlds[(wid * 4 + g) * 2048 + i * 512 + lane * 8];

    // ---- wave0: poll 256 hint-flags (1 KB; reload only missing) ----
    if (wid == 0) {
      const unsigned want = (unsigned)(ts + 1);
      unsigned f0 = 0, f1 = 0, f2 = 0, f3 = 0;
      for (;;) {
        if (f0 < want) f0 = __hip_atomic_load(&flags[lane],       __ATOMIC_RELAXED, __HIP_MEMORY_SCOPE_AGENT);
        if (f1 < want) f1 = __hip_atomic_load(&flags[lane +  64], __ATOMIC_RELAXED, __HIP_MEMORY_SCOPE_AGENT);
        if (f2 < want) f2 = __hip_atomic_load(&flags[lane + 128], __ATOMIC_RELAXED, __HIP_MEMORY_SCOPE_AGENT);
        if (f3 < want) f3 = __hip_atomic_load(&flags[lane + 192], __ATOMIC_RELAXED, __HIP_MEMORY_SCOPE_AGENT);
        if (f0 >= want && f1 >= want && f2 >= want && f3 >= want) break;
        __builtin_amdgcn_s_sleep(1);
      }
    }
    __syncthreads();           // hint seen; all waves past dot -> hA/hB free
    // ---- bulk read h_ts: 2x8B/thread, per-element sentinel retry ----
    const unsigned long long* src =
        (const unsigned long long*)(out + (size_t)ts * HDIM);
    unsigned long long r0, r1;
    do {
      r0 = __hip_atomic_load(src + t, __ATOMIC_RELAXED,
                             __HIP_MEMORY_SCOPE_AGENT);
    } while (((unsigned)r0 == SENT) | ((unsigned)(r0 >> 32) == SENT));
    do {
      r1 = __hip_atomic_load(src + t + 512, __ATOMIC_RELAXED,
                             __HIP_MEMORY_SCOPE_AGENT);
    } while (((unsigned)r1 == SENT) | ((unsigned)(r1 >> 32) == SENT));
    {
      const int k0 = 2 * t, k1 = 2 * t + 1024;
      const int i0 = k0 >> 9, r0i = (k0 >> 3) & 63, e0 = k0 & 7;
      const int i1 = k1 >> 9, r1i = (k1 >> 3) & 63, e1 = k1 & 7;
      float* d0 = ((e0 & 4) ? hB : hA) + i0 * 256 + r0i * 4 + (e0 & 3);
      float* d1 = ((e1 & 4) ? hB : hA) + i1 * 256 + r1i * 4 + (e1 & 3);
      d0[0] = __uint_as_float((unsigned)r0);
      d0[1] = __uint_as_float((unsigned)(r0 >> 32));
      d1[0] = __uint_as_float((unsigned)r1);
      d1[1] = __uint_as_float((unsigned)(r1 >> 32));
    }
    __syncthreads();           // hA/hB = h_ts ready
  }
}

// =====================================================================
extern "C" void kernel_launch(void* const* d_in, const int* in_sizes, int n_in,
                              void* d_out, int out_size, void* d_ws, size_t ws_size,
                              hipStream_t stream) {
  const float* x   = (const float*)d_in[0];
  const float* Wih = (const float*)d_in[1];
  const float* Whh = (const float*)d_in[2];
  const float* bih = (const float*)d_in[3];
  const float* bhh = (const float*)d_in[4];
  const float* h0  = (const float*)d_in[5];
  const float* c0  = (const float*)d_in[6];
  float* out = (float*)d_out;

  // ws layout: [0,1KB) flags | [32KB, +64MB) xg bf16
  unsigned* flags = (unsigned*)d_ws;
  unsigned short* xg = (unsigned short*)((char*)d_ws + 32768);

  hipMemsetAsync(flags, 0, NB * sizeof(unsigned), stream);

  fill_sentinel<<<dim3(2048), 256, 0, stream>>>((unsigned long long*)out);
  gemm_xg_mfma<<<dim3(2048), 256, 0, stream>>>(x, Wih, bih, bhh, xg);

  void* args[] = {(void*)&xg, (void*)&Whh, (void*)&h0,
                  (void*)&c0, (void*)&out, (void*)&flags};
  hipLaunchCooperativeKernel((void*)lstm_scan, dim3(NB), dim3(TPB),
                             args, 131072 /* dynamic LDS: Wlds */, stream);
}

// Round 11
// 16058.214 us; speedup vs baseline: 1.8982x; 1.0559x over previous
//
#include <hip/hip_runtime.h>
#include <hip/hip_bf16.h>

#define S_LEN 4096
#define IDIM  2048
#define HDIM  2048
#define G4    8192
#define NB    256
#define TPB   512
#define SENT  0x7FC00000u   // qNaN: h = sigmoid*tanh of finite data, never NaN

typedef __attribute__((ext_vector_type(2))) float  f32x2;
typedef __attribute__((ext_vector_type(4))) float  f32x4;
typedef __attribute__((ext_vector_type(8))) short  bf16x8;

// packed fp32 FMA: acc += w*h (2 MACs/instruction)
#define PKFMA(acc, w, h) \
  asm("v_pk_fma_f32 %0, %1, %2, %0" : "+v"(acc) : "v"(w), "v"(h))

// ---- bf16 helpers ----
__device__ __forceinline__ unsigned short f2bf(float f) {
  unsigned u = __float_as_uint(f);
  unsigned r = (u + 0x7FFFu + ((u >> 16) & 1u)) >> 16;   // RNE
  return (unsigned short)r;
}
__device__ __forceinline__ float bf2f(unsigned short h) {
  return __uint_as_float(((unsigned)h) << 16);
}
__device__ __forceinline__ f32x2 bfpair(unsigned u) {    // 2 packed bf16 -> f32x2
  f32x2 r;
  r.x = __uint_as_float(u << 16);
  r.y = __uint_as_float(u & 0xFFFF0000u);
  return r;
}
__device__ __forceinline__ f32x2 mk2(float a, float b) {
  f32x2 r; r.x = a; r.y = b; return r;
}
__device__ __forceinline__ float sigmoid_fast(float x) {
  return __builtin_amdgcn_rcpf(1.f + __expf(-x));
}
__device__ __forceinline__ float tanh_fast(float x) {
  return 1.f - 2.f * __builtin_amdgcn_rcpf(__expf(2.f * x) + 1.f);
}

// =====================================================================
// Kernel 0: fill out with sentinel (per-element readiness ground state)
// =====================================================================
__global__ __launch_bounds__(256) void fill_sentinel(unsigned long long* p) {
  const unsigned long long v =
      ((unsigned long long)SENT << 32) | (unsigned long long)SENT;
  const int n = S_LEN * HDIM / 2;
  for (int i = blockIdx.x * 256 + threadIdx.x; i < n; i += gridDim.x * 256)
    p[i] = v;
}

// =====================================================================
// Kernel 1: xg = x·W_ihᵀ + b_ih + b_hh, bf16 MFMA. (proven, ~0.1 ms)
// =====================================================================
#define BM 128
#define BKK 32
#define LDK 40

__global__ __launch_bounds__(256) void gemm_xg_mfma(
    const float* __restrict__ x, const float* __restrict__ Wih,
    const float* __restrict__ bih, const float* __restrict__ bhh,
    unsigned short* __restrict__ xg) {
  __shared__ unsigned short As[BM][LDK];
  __shared__ unsigned short Bs[BM][LDK];

  const int t = threadIdx.x;
  const int lane = t & 63, wid = t >> 6;
  const int wr = wid >> 1, wc = wid & 1;

  int bid = ((int)blockIdx.x & 7) * 256 + ((int)blockIdx.x >> 3);
  const int s0 = (bid >> 6) * BM;
  const int j0 = (bid & 63) * BM;

  f32x4 acc[4][4] = {};

  float bias[4];
#pragma unroll
  for (int n = 0; n < 4; ++n) {
    const int col = j0 + wc * 64 + n * 16 + (lane & 15);
    bias[n] = bih[col] + bhh[col];
  }

  for (int k0 = 0; k0 < IDIM; k0 += BKK) {
    float4 va[4], vb[4];
#pragma unroll
    for (int u = 0; u < 4; ++u) {
      const int f = t + 256 * u;
      const int row = f >> 3, kc = (f & 7) * 4;
      va[u] = *(const float4*)&x  [(size_t)(s0 + row) * IDIM + k0 + kc];
      vb[u] = *(const float4*)&Wih[(size_t)(j0 + row) * IDIM + k0 + kc];
    }
    __syncthreads();
#pragma unroll
    for (int u = 0; u < 4; ++u) {
      const int f = t + 256 * u;
      const int row = f >> 3, kc = (f & 7) * 4;
      ushort4 pa, pb;
      pa.x = f2bf(va[u].x); pa.y = f2bf(va[u].y);
      pa.z = f2bf(va[u].z); pa.w = f2bf(va[u].w);
      pb.x = f2bf(vb[u].x); pb.y = f2bf(vb[u].y);
      pb.z = f2bf(vb[u].z); pb.w = f2bf(vb[u].w);
      *(ushort4*)&As[row][kc] = pa;
      *(ushort4*)&Bs[row][kc] = pb;
    }
    __syncthreads();

    const int fr = lane & 15, koff = (lane >> 4) * 8;
    bf16x8 a[4], bfr[4];
#pragma unroll
    for (int m = 0; m < 4; ++m)
      a[m] = *(const bf16x8*)&As[wr * 64 + m * 16 + fr][koff];
#pragma unroll
    for (int n = 0; n < 4; ++n)
      bfr[n] = *(const bf16x8*)&Bs[wc * 64 + n * 16 + fr][koff];
#pragma unroll
    for (int m = 0; m < 4; ++m)
#pragma unroll
      for (int n = 0; n < 4; ++n)
        acc[m][n] = __builtin_amdgcn_mfma_f32_16x16x32_bf16(
            a[m], bfr[n], acc[m][n], 0, 0, 0);
  }

#pragma unroll
  for (int m = 0; m < 4; ++m) {
    const int row0 = s0 + wr * 64 + m * 16 + (lane >> 4) * 4;
#pragma unroll
    for (int n = 0; n < 4; ++n) {
      const int col = j0 + wc * 64 + n * 16 + (lane & 15);
#pragma unroll
      for (int r = 0; r < 4; ++r)
        xg[(size_t)(row0 + r) * G4 + col] = f2bf(acc[m][n][r] + bias[n]);
    }
  }
}

// =====================================================================
// Kernel 2: persistent scan — LDS-resident bf16 weights (structural,
// r10) + per-step pinned register prefetch (the r1-r10 lesson chain:
// arrays spill; named scalars remat; one-time pins spill; per-use asm
// serializes; dynamic-LDS blinds the occupancy heuristic so (512,2)
// still minimized VGPRs to 68. Fix: (512,1) budget + loop-interior
// pins => 64 live VGPRs are non-remattable and cheapest to KEEP).
//  Schedule: [h ready] dot -> act -> publish -> raw s_barrier -> flag
//  -> WPREF (16 ds_read_b128 + pins; completes under poll) -> wave0
//  flag-poll -> bar -> sentinel-verified bulk h read -> stage -> bar.
//  k-map: lane l covers k = i*512 + 8l + e (e<8); W LDS row per
//  (unit,gate) at ushort (wid*4+g)*2048 + i*512 + l*8 — all LDS traffic
//  is lane-contiguous b128.
// =====================================================================

#define LDW(g, i) \
  (*(const uint4*)&Wlds[(wid * 4 + (g)) * 2048 + (i) * 512 + lane * 8])
#define PIN4(v) \
  asm volatile("" : "+v"(v.x), "+v"(v.y), "+v"(v.z), "+v"(v.w))
#define WPREF do { \
  w00 = LDW(0,0); w01 = LDW(0,1); w02 = LDW(0,2); w03 = LDW(0,3); \
  w10 = LDW(1,0); w11 = LDW(1,1); w12 = LDW(1,2); w13 = LDW(1,3); \
  w20 = LDW(2,0); w21 = LDW(2,1); w22 = LDW(2,2); w23 = LDW(2,3); \
  w30 = LDW(3,0); w31 = LDW(3,1); w32 = LDW(3,2); w33 = LDW(3,3); \
  PIN4(w00); PIN4(w01); PIN4(w02); PIN4(w03); \
  PIN4(w10); PIN4(w11); PIN4(w12); PIN4(w13); \
  PIN4(w20); PIN4(w21); PIN4(w22); PIN4(w23); \
  PIN4(w30); PIN4(w31); PIN4(w32); PIN4(w33); \
} while (0)

#define DGC(Acc, W, HA, HB) do { \
  PKFMA(Acc, bfpair(W.x), mk2(HA.x, HA.y)); \
  PKFMA(Acc, bfpair(W.y), mk2(HA.z, HA.w)); \
  PKFMA(Acc, bfpair(W.z), mk2(HB.x, HB.y)); \
  PKFMA(Acc, bfpair(W.w), mk2(HB.z, HB.w)); \
} while (0)

__global__ __launch_bounds__(TPB, 1) void lstm_scan(
    const unsigned short* __restrict__ xg, const float* __restrict__ Whh,
    const float* __restrict__ h0, const float* __restrict__ c0,
    float* __restrict__ out, unsigned* __restrict__ flags) {
  extern __shared__ unsigned short Wlds[];    // 128 KB dynamic
  __shared__ __align__(16) float h_sh[HDIM];  // 8 KB static

  const int b = blockIdx.x, t = threadIdx.x;
  const int lane = t & 63, wid = t >> 6;
  const int j = b * 8 + wid;                  // this wave's unit

  // ---- one-time: weights -> LDS (bf16), lane-contiguous rows ----
#pragma unroll
  for (int g = 0; g < 4; ++g) {
    const float* wp = Whh + ((size_t)g * HDIM + j) * HDIM;
#pragma unroll
    for (int i = 0; i < 4; ++i) {
      const float4 q0 = *(const float4*)(wp + i * 512 + lane * 8);
      const float4 q1 = *(const float4*)(wp + i * 512 + lane * 8 + 4);
      uint4 pk;
      pk.x = (unsigned)f2bf(q0.x) | ((unsigned)f2bf(q0.y) << 16);
      pk.y = (unsigned)f2bf(q0.z) | ((unsigned)f2bf(q0.w) << 16);
      pk.z = (unsigned)f2bf(q1.x) | ((unsigned)f2bf(q1.y) << 16);
      pk.w = (unsigned)f2bf(q1.z) | ((unsigned)f2bf(q1.w) << 16);
      *(uint4*)&Wlds[(wid * 4 + g) * 2048 + i * 512 + lane * 8] = pk;
    }
  }

  // stage h0 (plain layout)
  h_sh[t]        = h0[t];
  h_sh[t + 512]  = h0[t + 512];
  h_sh[t + 1024] = h0[t + 1024];
  h_sh[t + 1536] = h0[t + 1536];
  __syncthreads();                            // weights + h0 staged

  float c_reg = (lane == 0) ? c0[j] : 0.f;

  uint4 w00, w01, w02, w03, w10, w11, w12, w13,
        w20, w21, w22, w23, w30, w31, w32, w33;
  WPREF;                                      // prologue prefetch (step 0)

  for (int ts = 0; ts < S_LEN; ++ts) {
    // xg prefetch (lanes 0-3: this unit's 4 gate pre-activations)
    float xgv = 0.f;
    if (lane < 4)
      xgv = bf2f(xg[(size_t)ts * G4 + (size_t)lane * HDIM + j]);

    // ---- h reads: 8 lane-contiguous b128 (plain layout) ----
    const f32x4 ha0 = *(const f32x4*)&h_sh[0 * 512 + lane * 8];
    const f32x4 hb0 = *(const f32x4*)&h_sh[0 * 512 + lane * 8 + 4];
    const f32x4 ha1 = *(const f32x4*)&h_sh[1 * 512 + lane * 8];
    const f32x4 hb1 = *(const f32x4*)&h_sh[1 * 512 + lane * 8 + 4];
    const f32x4 ha2 = *(const f32x4*)&h_sh[2 * 512 + lane * 8];
    const f32x4 hb2 = *(const f32x4*)&h_sh[2 * 512 + lane * 8 + 4];
    const f32x4 ha3 = *(const f32x4*)&h_sh[3 * 512 + lane * 8];
    const f32x4 hb3 = *(const f32x4*)&h_sh[3 * 512 + lane * 8 + 4];

    // ---- dot: 64 pk_fma, weights from pinned prefetch regs ----
    f32x2 A0 = {0.f, 0.f}, A1 = {0.f, 0.f}, A2 = {0.f, 0.f}, A3 = {0.f, 0.f};
    DGC(A0, w00, ha0, hb0); DGC(A0, w01, ha1, hb1);
    DGC(A0, w02, ha2, hb2); DGC(A0, w03, ha3, hb3);
    DGC(A1, w10, ha0, hb0); DGC(A1, w11, ha1, hb1);
    DGC(A1, w12, ha2, hb2); DGC(A1, w13, ha3, hb3);
    DGC(A2, w20, ha0, hb0); DGC(A2, w21, ha1, hb1);
    DGC(A2, w22, ha2, hb2); DGC(A2, w23, ha3, hb3);
    DGC(A3, w30, ha0, hb0); DGC(A3, w31, ha1, hb1);
    DGC(A3, w32, ha2, hb2); DGC(A3, w33, ha3, hb3);

    float a0 = A0.x + A0.y, a1 = A1.x + A1.y;
    float a2 = A2.x + A2.y, a3 = A3.x + A3.y;
#pragma unroll
    for (int m = 1; m < 64; m <<= 1) {
      a0 += __shfl_xor(a0, m);
      a1 += __shfl_xor(a1, m);
      a2 += __shfl_xor(a2, m);
      a3 += __shfl_xor(a3, m);
    }
    float sv = (lane == 0) ? a0 : (lane == 1) ? a1 : (lane == 2) ? a2 : a3;
    sv += xgv;
    const float av = (lane == 2) ? tanh_fast(sv) : sigmoid_fast(sv);
    const float iv = __shfl(av, 0);
    const float fv = __shfl(av, 1);
    const float gv = __shfl(av, 2);
    const float ov = __shfl(av, 3);
    if (lane == 0) {
      c_reg = fmaf(fv, c_reg, iv * gv);
      const float hn = ov * tanh_fast(c_reg);
      __hip_atomic_store(&out[(size_t)ts * HDIM + j], hn,
                         __ATOMIC_RELAXED, __HIP_MEMORY_SCOPE_AGENT);
    }
    // raw barrier (no vmcnt drain); then flag hint
    __builtin_amdgcn_s_barrier();
    if (t == 0)
      __hip_atomic_store(&flags[b], (unsigned)(ts + 1),
                         __ATOMIC_RELAXED, __HIP_MEMORY_SCOPE_AGENT);

    if (ts + 1 == S_LEN) break;

    // ---- w-prefetch for ts+1: issues + pins NOW, completes under poll ----
    WPREF;

    // ---- wave0: poll 256 hint-flags (1 KB; reload only missing) ----
    if (wid == 0) {
      const unsigned want = (unsigned)(ts + 1);
      unsigned f0 = 0, f1 = 0, f2 = 0, f3 = 0;
      for (;;) {
        if (f0 < want) f0 = __hip_atomic_load(&flags[lane],       __ATOMIC_RELAXED, __HIP_MEMORY_SCOPE_AGENT);
        if (f1 < want) f1 = __hip_atomic_load(&flags[lane +  64], __ATOMIC_RELAXED, __HIP_MEMORY_SCOPE_AGENT);
        if (f2 < want) f2 = __hip_atomic_load(&flags[lane + 128], __ATOMIC_RELAXED, __HIP_MEMORY_SCOPE_AGENT);
        if (f3 < want) f3 = __hip_atomic_load(&flags[lane + 192], __ATOMIC_RELAXED, __HIP_MEMORY_SCOPE_AGENT);
        if (f0 >= want && f1 >= want && f2 >= want && f3 >= want) break;
        __builtin_amdgcn_s_sleep(1);
      }
    }
    __syncthreads();           // hint seen; all waves past dot -> h_sh free
    // ---- bulk read h_ts: 2x8B/thread, per-element sentinel retry ----
    const unsigned long long* src =
        (const unsigned long long*)(out + (size_t)ts * HDIM);
    unsigned long long r0, r1;
    do {
      r0 = __hip_atomic_load(src + t, __ATOMIC_RELAXED,
                             __HIP_MEMORY_SCOPE_AGENT);
    } while (((unsigned)r0 == SENT) | ((unsigned)(r0 >> 32) == SENT));
    do {
      r1 = __hip_atomic_load(src + t + 512, __ATOMIC_RELAXED,
                             __HIP_MEMORY_SCOPE_AGENT);
    } while (((unsigned)r1 == SENT) | ((unsigned)(r1 >> 32) == SENT));
    h_sh[2*t]        = __uint_as_float((unsigned)r0);
    h_sh[2*t + 1]    = __uint_as_float((unsigned)(r0 >> 32));
    h_sh[2*t + 1024] = __uint_as_float((unsigned)r1);
    h_sh[2*t + 1025] = __uint_as_float((unsigned)(r1 >> 32));
    __syncthreads();           // h_sh = h_ts ready
  }
}

// =====================================================================
extern "C" void kernel_launch(void* const* d_in, const int* in_sizes, int n_in,
                              void* d_out, int out_size, void* d_ws, size_t ws_size,
                              hipStream_t stream) {
  const float* x   = (const float*)d_in[0];
  const float* Wih = (const float*)d_in[1];
  const float* Whh = (const float*)d_in[2];
  const float* bih = (const float*)d_in[3];
  const float* bhh = (const float*)d_in[4];
  const float* h0  = (const float*)d_in[5];
  const float* c0  = (const float*)d_in[6];
  float* out = (float*)d_out;

  // ws layout: [0,1KB) flags | [32KB, +64MB) xg bf16
  unsigned* flags = (unsigned*)d_ws;
  unsigned short* xg = (unsigned short*)((char*)d_ws + 32768);

  hipMemsetAsync(flags, 0, NB * sizeof(unsigned), stream);

  fill_sentinel<<<dim3(2048), 256, 0, stream>>>((unsigned long long*)out);
  gemm_xg_mfma<<<dim3(2048), 256, 0, stream>>>(x, Wih, bih, bhh, xg);

  void* args[] = {(void*)&xg, (void*)&Whh, (void*)&h0,
                  (void*)&c0, (void*)&out, (void*)&flags};
  hipLaunchCooperativeKernel((void*)lstm_scan, dim3(NB), dim3(TPB),
                             args, 131072 /* dynamic LDS: Wlds */, stream);
}